// Round 8
// baseline (165.635 us; speedup 1.0000x reference)
//
#include <hip/hip_runtime.h>
#include <cstdint>

typedef __attribute__((ext_vector_type(8))) short short8;
typedef __attribute__((ext_vector_type(16))) float f32x16;

__device__ inline uint32_t f2bf(float f) {
    union { float f; uint32_t u; } x; x.f = f;
    return (x.u + 0x7FFF + ((x.u >> 16) & 1)) >> 16;
}

// Convert kernel fp32 [9][64][64] -> bf16 ktb (same order), init bias outputs.
__global__ void k_prep(const float* __restrict__ kk, uint16_t* __restrict__ ktb,
                       const float* __restrict__ buI, const float* __restrict__ blI,
                       float* __restrict__ buO, float* __restrict__ blO) {
    int i = blockIdx.x * 256 + threadIdx.x;
    if (i < 36864) ktb[i] = (uint16_t)f2bf(kk[i]);
    else if (i < 36864 + 256) buO[i - 36864] = buI[i - 36864];
    else if (i < 36864 + 512) blO[i - 36864 - 256] = blI[i - 36864 - 256];
}

// Block: (b, UL, h, w-chunk of 8). 4 waves.
// T14 pipeline: issue row r+1 loads -> compute row r -> write row r+1 -> barrier.
// LDS: 2 row-buffers x 10 sites x 4096 B = 81920 B exactly -> 2 blocks/CU.
__global__ __launch_bounds__(256, 2) void k_main(
    const float* __restrict__ wu, const float* __restrict__ wl,
    const uint16_t* __restrict__ ktb, const float* __restrict__ bias,
    float* __restrict__ outU, float* __restrict__ outL,
    float* __restrict__ buO, float* __restrict__ blO)
{
    __shared__ uint16_t tiles[2][10][2048];   // 81920 B exactly

    int t  = threadIdx.x;
    int l  = t & 63;
    int wv = t >> 6;
    int o  = l & 31;            // n_out index (frag col, stride-1 in memory)
    int ch = l >> 5;            // co-half selector (compute phase)

    // staging lane geometry: q = o-quad, g = co-pair index
    int q  = l & 7;             // o0 = 4q
    int g  = l >> 3;            // co = 2g + 16p
    int o0 = q * 4;

    // XCD-chunk swizzle: h innermost within an XCD's contiguous chunk
    int bid  = blockIdx.x;
    int virt = (bid & 7) * 256 + (bid >> 3);
    int h    = virt & 31;
    int wc   = (virt >> 5) & 3;
    int UL   = (virt >> 7) & 1;
    int b    = virt >> 8;
    int w0   = wc * 8;

    const float* src = UL ? wl : wu;
    float* dst  = UL ? outL : outU;
    float* bdst = UL ? blO : buO;

    // contiguous per-wave site lists: [0,1,2] [3,4,5] [6,7] [8,9]
    int s0 = (wv < 2) ? 3 * wv : 6 + 2 * (wv - 2);
    int ns = (wv < 2) ? 3 : 2;

    // valid kh rows: hh = h+1-r in [0,32)
    int rstart = (h == 31) ? 1 : 0;
    int nr     = (h == 0 || h == 31) ? 2 : 3;

    // bias values for this thread's co pairs
    float2 breg[4];
    #pragma unroll
    for (int p = 0; p < 4; p++)
        breg[p] = *(const float2*)(bias + 2 * g + 16 * p);

    float bp[4] = {0.f, 0.f, 0.f, 0.f};

    f32x16 acc[2][2];
    #pragma unroll
    for (int a = 0; a < 2; a++)
        #pragma unroll
        for (int c = 0; c < 2; c++) acc[a][c] = (f32x16)0.f;

    float4 gA[3][4], gB[3][4];   // in-flight row batch (<=24 float4)

    // ---- issue all global loads for this wave's sites of row r ----
    auto LOAD = [&](int RR) {
        int hh_ = h + 1 - RR;
        #pragma unroll
        for (int i_ = 0; i_ < 3; i_++) {
            if (i_ < ns) {
                int ww_ = w0 - 1 + s0 + i_;
                if ((unsigned)ww_ < 32u) {
                    const float* base_ = src + ((size_t)b * 65536
                                      + (size_t)(hh_ * 32 + ww_) * 64) * 32;
                    #pragma unroll
                    for (int p = 0; p < 4; p++) {
                        int co_ = 2 * g + 16 * p;
                        gA[i_][p] = *(const float4*)(base_ + co_ * 32 + o0);
                        gB[i_][p] = *(const float4*)(base_ + (co_ + 1) * 32 + o0);
                    }
                }
            }
        }
    };

    // ---- pack batch -> LDS buf (zeros for OOB sites), bias fma ----
    auto WRITE = [&](int BUF, int RR) {
        char* lb_ = (char*)&tiles[BUF][0][0];
        #pragma unroll
        for (int i_ = 0; i_ < 3; i_++) {
            if (i_ < ns) {
                int s_  = s0 + i_;
                int ww_ = w0 - 1 + s_;
                char* lp_ = lb_ + s_ * 4096;
                if ((unsigned)ww_ >= 32u) {
                    #pragma unroll
                    for (int p = 0; p < 4; p++) {
                        int co_ = 2 * g + 16 * p;
                        int chunk_ = (g >> 2) + 2 * p;
                        int cb_ = (co_ & 7) << 1;
                        #pragma unroll
                        for (int dd = 0; dd < 4; dd++) {
                            int oo_ = o0 + dd;
                            *(uint32_t*)(lp_ + oo_ * 128
                                + ((chunk_ ^ (oo_ & 7)) << 4) + cb_) = 0u;
                        }
                    }
                } else {
                    bool ctr_ = (RR == 1) && (s_ >= 1) && (s_ <= 8);
                    #pragma unroll
                    for (int p = 0; p < 4; p++) {
                        int co_ = 2 * g + 16 * p;
                        int chunk_ = (g >> 2) + 2 * p;
                        int cb_ = (co_ & 7) << 1;
                        if (ctr_) {
                            bp[0] = fmaf(gA[i_][p].x, breg[p].x,
                                    fmaf(gB[i_][p].x, breg[p].y, bp[0]));
                            bp[1] = fmaf(gA[i_][p].y, breg[p].x,
                                    fmaf(gB[i_][p].y, breg[p].y, bp[1]));
                            bp[2] = fmaf(gA[i_][p].z, breg[p].x,
                                    fmaf(gB[i_][p].z, breg[p].y, bp[2]));
                            bp[3] = fmaf(gA[i_][p].w, breg[p].x,
                                    fmaf(gB[i_][p].w, breg[p].y, bp[3]));
                        }
                        uint32_t dw_[4];
                        dw_[0] = f2bf(gA[i_][p].x) | (f2bf(gB[i_][p].x) << 16);
                        dw_[1] = f2bf(gA[i_][p].y) | (f2bf(gB[i_][p].y) << 16);
                        dw_[2] = f2bf(gA[i_][p].z) | (f2bf(gB[i_][p].z) << 16);
                        dw_[3] = f2bf(gA[i_][p].w) | (f2bf(gB[i_][p].w) << 16);
                        #pragma unroll
                        for (int dd = 0; dd < 4; dd++) {
                            int oo_ = o0 + dd;
                            *(uint32_t*)(lp_ + oo_ * 128
                                + ((chunk_ ^ (oo_ & 7)) << 4) + cb_) = dw_[dd];
                        }
                    }
                }
            }
        }
    };

    // ---- prologue: stage first valid row into buf 0 ----
    LOAD(rstart);
    WRITE(0, rstart);
    __syncthreads();

    for (int i = 0; i < nr; i++) {
        int r = rstart + i;

        if (i + 1 < nr) LOAD(r + 1);          // T14: issue early

        // ---- compute row r from tiles[i&1] (verified indexing) ----
        const uint16_t* tb = &tiles[i & 1][0][0];
        #pragma unroll
        for (int kidx = 0; kidx < 4; kidx++) {
            short8 A[3][2];
            #pragma unroll
            for (int kw = 0; kw < 3; kw++)
                #pragma unroll
                for (int c = 0; c < 2; c++)
                    A[kw][c] = *(const short8*)&ktb[(((r * 3 + kw) * 64) + c * 32 + (l & 31)) * 64
                                                    + kidx * 16 + ch * 8];
            #pragma unroll
            for (int si = 0; si < 4; si++) {
                int s = 2 * wv + si;
                int chunk = kidx * 2 + ch;
                short8 Bf = *(const short8*)&tb[s * 2048 + o * 64 + ((chunk ^ (o & 7)) << 3)];
                #pragma unroll
                for (int tw = 0; tw < 2; tw++) {
                    int kw = tw + 2 - si;              // compile-time under unroll
                    if (kw >= 0 && kw <= 2) {
                        #pragma unroll
                        for (int c = 0; c < 2; c++)
                            acc[tw][c] = __builtin_amdgcn_mfma_f32_32x32x16_bf16(
                                A[kw][c], Bf, acc[tw][c], 0, 0, 0);
                    }
                }
            }
        }

        if (i + 1 < nr) WRITE((i + 1) & 1, r + 1);   // T14: write late (auto vmcnt)
        __syncthreads();
    }

    // ---- bias reduction: shfl pre-reduce (lanes sharing o differ in g bits) ----
    #pragma unroll
    for (int dd = 0; dd < 4; dd++) {
        float v = bp[dd];
        v += __shfl_xor(v, 8);
        v += __shfl_xor(v, 16);
        v += __shfl_xor(v, 32);
        bp[dd] = v;
    }
    float* bsum = (float*)&tiles[0][0][0];
    if (t < 32) bsum[t] = 0.f;
    __syncthreads();
    if (g == 0) {
        #pragma unroll
        for (int dd = 0; dd < 4; dd++) atomicAdd(&bsum[4 * q + dd], bp[dd]);
    }
    __syncthreads();
    if (t < 32) atomicAdd(&bdst[b * 32 + t], bsum[t]);

    // ---- stores: col = o (coalesced), row = (reg&3)+8*(reg>>2)+4*(lane>>5) ----
    int wa = w0 + 2 * wv;
    #pragma unroll
    for (int tw = 0; tw < 2; tw++) {
        int w = wa + tw;
        #pragma unroll
        for (int c = 0; c < 2; c++) {
            float* base = dst + ((size_t)b * 65536 + (size_t)(h * 32 + w) * 64 + c * 32) * 32;
            #pragma unroll
            for (int reg = 0; reg < 16; reg++) {
                int row = (reg & 3) + 8 * (reg >> 2) + 4 * (l >> 5);
                base[row * 32 + o] = acc[tw][c][reg];
            }
        }
    }
}

extern "C" void kernel_launch(void* const* d_in, const int* in_sizes, int n_in,
                              void* d_out, int out_size, void* d_ws, size_t ws_size,
                              hipStream_t stream) {
    const float* wu   = (const float*)d_in[1];
    const float* buI  = (const float*)d_in[2];
    const float* wl   = (const float*)d_in[3];
    const float* blI  = (const float*)d_in[4];
    const float* kk   = (const float*)d_in[5];
    const float* bias = (const float*)d_in[6];

    float* out  = (float*)d_out;
    float* outU = out;
    float* buO  = out + 16777216;
    float* outL = out + 16777216 + 256;
    float* blO  = out + 2 * 16777216 + 256;

    uint16_t* ktb = (uint16_t*)d_ws;   // 73728 B

    k_prep<<<146, 256, 0, stream>>>(kk, ktb, buI, blI, buO, blO);
    k_main<<<2048, 256, 0, stream>>>(wu, wl, ktb, bias, outU, outL, buO, blO);
}

// Round 9
// 119.551 us; speedup vs baseline: 1.3855x; 1.3855x over previous
//
#include <hip/hip_runtime.h>
#include <cstdint>

typedef __attribute__((ext_vector_type(8))) short short8;
typedef __attribute__((ext_vector_type(16))) float f32x16;

__device__ inline uint32_t f2bf(float f) {
    union { float f; uint32_t u; } x; x.f = f;
    return (x.u + 0x7FFF + ((x.u >> 16) & 1)) >> 16;
}

// Convert kernel fp32 [9][64][64] -> bf16 ktb (same order), init bias outputs.
__global__ void k_prep(const float* __restrict__ kk, uint16_t* __restrict__ ktb,
                       const float* __restrict__ buI, const float* __restrict__ blI,
                       float* __restrict__ buO, float* __restrict__ blO) {
    int i = blockIdx.x * 256 + threadIdx.x;
    if (i < 36864) ktb[i] = (uint16_t)f2bf(kk[i]);
    else if (i < 36864 + 256) buO[i - 36864] = buI[i - 36864];
    else if (i < 36864 + 512) blO[i - 36864 - 256] = blI[i - 36864 - 256];
}

// Block: (b, UL, h, w-chunk of 8) = 4 fully-independent waves (no LDS, no barriers).
// Wave owns 2 output w's; B-fragments loaded DIRECTLY from global in MFMA layout:
// lane l: col o = l&31, k-elems co = kidx*16 + (l>>5)*8 + e  (8 dword loads, imm offsets).
__global__ __launch_bounds__(256, 2) void k_main(
    const float* __restrict__ wu, const float* __restrict__ wl,
    const uint16_t* __restrict__ ktb, const float* __restrict__ bias,
    float* __restrict__ outU, float* __restrict__ outL,
    float* __restrict__ buO, float* __restrict__ blO)
{
    int t  = threadIdx.x;
    int l  = t & 63;
    int wv = t >> 6;
    int o  = l & 31;            // n_out index (frag col, stride-1 in memory)
    int ch = l >> 5;            // co-band selector

    // XCD-chunk swizzle: h innermost within an XCD's contiguous chunk
    int bid  = blockIdx.x;
    int virt = (bid & 7) * 256 + (bid >> 3);
    int h    = virt & 31;
    int wc   = (virt >> 5) & 3;
    int UL   = (virt >> 7) & 1;
    int b    = virt >> 8;
    int w0   = wc * 8 + 2 * wv;   // wave's first owned w

    const float* src = UL ? wl : wu;
    float* dst  = UL ? outL : outU;
    float* bdst = UL ? blO : buO;

    float bp = 0.f;               // bias partial (this lane's o, its co-band)

    f32x16 acc[2][2];             // [tw][ci-half]
    #pragma unroll
    for (int a = 0; a < 2; a++)
        #pragma unroll
        for (int c = 0; c < 2; c++) acc[a][c] = (f32x16)0.f;

    // site validity (wave-uniform): ww = w0-1+si
    bool sv0 = (w0 != 0);         // si=0 OOB only when w0==0
    bool sv3 = (w0 != 30);        // si=3 OOB only when w0+2==32

    for (int r = 0; r < 3; r++) {
        int hh = h + 1 - r;                 // adjoint: out row h reads conv row h+1-kh
        if ((unsigned)hh >= 32u) continue;  // wave-uniform

        // per-site lane base pointers (floats): + co*32 + o, co = kidx*16 + ch*8 + e
        const float* sb[4];
        #pragma unroll
        for (int si = 0; si < 4; si++) {
            int ww = w0 - 1 + si;
            int wwc = ((unsigned)ww < 32u) ? ww : 0;
            sb[si] = src + ((size_t)b * 65536 + (size_t)(hh * 32 + wwc) * 64) * 32
                         + ch * 256 + o;
        }

        #pragma unroll
        for (int kidx = 0; kidx < 4; kidx++) {
            // A-fragments (verified layout), 6 x 16B from bf16 kernel
            short8 A[3][2];
            #pragma unroll
            for (int kw = 0; kw < 3; kw++)
                #pragma unroll
                for (int c = 0; c < 2; c++)
                    A[kw][c] = *(const short8*)&ktb[(((r * 3 + kw) * 64) + c * 32 + (l & 31)) * 64
                                                    + kidx * 16 + ch * 8];

            // issue all 4 sites' B loads (8 dwords each, imm-offset folded)
            float g[4][8];
            #pragma unroll
            for (int si = 0; si < 4; si++) {
                bool valid = (si == 0) ? sv0 : (si == 3) ? sv3 : true;
                if (valid) {
                    #pragma unroll
                    for (int e = 0; e < 8; e++)
                        g[si][e] = sb[si][kidx * 512 + e * 32];
                } else {
                    #pragma unroll
                    for (int e = 0; e < 8; e++) g[si][e] = 0.f;
                }
            }

            // bias: center row, wave's own columns (si=1 -> w0, si=2 -> w0+1)
            if (r == 1) {
                float4 b0 = *(const float4*)(bias + kidx * 16 + ch * 8);
                float4 b1 = *(const float4*)(bias + kidx * 16 + ch * 8 + 4);
                float bb[8] = {b0.x, b0.y, b0.z, b0.w, b1.x, b1.y, b1.z, b1.w};
                #pragma unroll
                for (int e = 0; e < 8; e++)
                    bp = fmaf(g[1][e], bb[e], fmaf(g[2][e], bb[e], bp));
            }

            // pack + MFMA
            #pragma unroll
            for (int si = 0; si < 4; si++) {
                short8 Bf;
                #pragma unroll
                for (int e = 0; e < 8; e++) Bf[e] = (short)(uint16_t)f2bf(g[si][e]);
                #pragma unroll
                for (int tw = 0; tw < 2; tw++) {
                    int kw = tw + 2 - si;              // compile-time under unroll
                    if (kw >= 0 && kw <= 2) {
                        #pragma unroll
                        for (int c = 0; c < 2; c++)
                            acc[tw][c] = __builtin_amdgcn_mfma_f32_32x32x16_bf16(
                                A[kw][c], Bf, acc[tw][c], 0, 0, 0);
                    }
                }
            }
        }
    }

    // ---- bias reduction: lanes l and l^32 share o ----
    bp += __shfl_xor(bp, 32);
    if (l < 32) atomicAdd(&bdst[b * 32 + o], bp);

    // ---- stores: col = o (coalesced), row = (reg&3)+8*(reg>>2)+4*(lane>>5) ----
    #pragma unroll
    for (int tw = 0; tw < 2; tw++) {
        int w = w0 + tw;
        #pragma unroll
        for (int c = 0; c < 2; c++) {
            float* base = dst + ((size_t)b * 65536 + (size_t)(h * 32 + w) * 64 + c * 32) * 32;
            #pragma unroll
            for (int reg = 0; reg < 16; reg++) {
                int row = (reg & 3) + 8 * (reg >> 2) + 4 * (l >> 5);
                base[row * 32 + o] = acc[tw][c][reg];
            }
        }
    }
}

extern "C" void kernel_launch(void* const* d_in, const int* in_sizes, int n_in,
                              void* d_out, int out_size, void* d_ws, size_t ws_size,
                              hipStream_t stream) {
    const float* wu   = (const float*)d_in[1];
    const float* buI  = (const float*)d_in[2];
    const float* wl   = (const float*)d_in[3];
    const float* blI  = (const float*)d_in[4];
    const float* kk   = (const float*)d_in[5];
    const float* bias = (const float*)d_in[6];

    float* out  = (float*)d_out;
    float* outU = out;
    float* buO  = out + 16777216;
    float* outL = out + 16777216 + 256;
    float* blO  = out + 2 * 16777216 + 256;

    uint16_t* ktb = (uint16_t*)d_ws;   // 73728 B

    k_prep<<<146, 256, 0, stream>>>(kk, ktb, buI, blI, buO, blO);
    k_main<<<2048, 256, 0, stream>>>(wu, wl, ktb, bias, outU, outL, buO, blO);
}